// Round 12
// baseline (551.384 us; speedup 1.0000x reference)
//
#include <hip/hip_runtime.h>
#include <hip/hip_cooperative_groups.h>

namespace cg = cooperative_groups;

// AssociativeScanGateLoop: h_t = f_t*h_{t-1} + i_t*v_t per (b,d) sequence.
// x: (B=4, T=8192, 3*512) fp32.  out: (4, 8192, 512) fp32.
//
// v5: single cooperative kernel (3-phase, grid.sync between phases).
// Round-10 accounting: the 3 separate kernels each ran <118us yet total was
// 316us => >=75us of inter-dispatch overhead, and per-kernel counters were
// invisible (fills crowd top-5). Fusing eliminates the gaps, lets phase 3
// re-read xi/gi from L3, and surfaces one big dispatch WITH counters.

#define B_   4
#define T_   8192
#define DH_  512
#define ROW_ 1536
#define C_   256
#define TC_  32          // T_ / C_

// clang ext-vector: __builtin_nontemporal_store requires this, not HIP float4.
typedef float f32x4 __attribute__((ext_vector_type(4)));

__device__ __forceinline__ float rcp_f(float x) {
    return __builtin_amdgcn_rcpf(x);   // v_rcp_f32 — avoids div expansion
}
__device__ __forceinline__ float sigmoid_f(float x) {
    return rcp_f(1.0f + __expf(-x));
}
__device__ __forceinline__ float tanh_f(float x) {
    // 1 - 2/(e^{2x}+1): saturates to +/-1 even when __expf overflows to inf.
    return 1.0f - 2.0f * rcp_f(__expf(2.0f * x) + 1.0f);
}

// Fused: phase1 chunk aggregates -> grid.sync -> phase2 Kogge-Stone scan of
// affine maps per channel -> grid.sync -> phase3 recompute + gated output.
// Block (c, b): phase1/3 own chunk c of batch b; phase2 owns channels 2c,2c+1.
__global__ __launch_bounds__(128, 2)
void k_fused(const float* __restrict__ x,
             float* __restrict__ out,
             float* __restrict__ agg_a,
             float* __restrict__ agg_kv,
             float* __restrict__ h0) {
    const int c  = blockIdx.x;           // chunk index [0, C_)
    const int b  = blockIdx.y;           // batch
    const int d4 = threadIdx.x << 2;     // channel base (4 per thread)
    const int t  = threadIdx.x;

    __shared__ float sa[128];
    __shared__ float sk[128];

    const float* xb = x + ((size_t)b * T_ + (size_t)c * TC_) * ROW_;

    // ---------------- phase 1: per-chunk affine aggregate (A, KV)
    {
        float A[4] = {1.f, 1.f, 1.f, 1.f};
        float K[4] = {0.f, 0.f, 0.f, 0.f};
#pragma unroll 8
        for (int i = 0; i < TC_; ++i) {
            const float* r = xb + (size_t)i * ROW_;
            const f32x4 xi = *(const f32x4*)(r + d4);
            const f32x4 gi = *(const f32x4*)(r + DH_ + d4);
#pragma unroll
            for (int j = 0; j < 4; ++j) {
                const float s  = sigmoid_f(gi[j]);
                const float f  = 1.0f - s;
                const float iv = tanh_f(xi[j]) * s;
                A[j] = f * A[j];
                K[j] = fmaf(f, K[j], iv);
            }
        }
        const size_t idx = ((size_t)b * C_ + c) * DH_ + d4;
        f32x4 Av = {A[0], A[1], A[2], A[3]};
        f32x4 Kv = {K[0], K[1], K[2], K[3]};
        *(f32x4*)(agg_a + idx)  = Av;
        *(f32x4*)(agg_kv + idx) = Kv;
    }

    cg::this_grid().sync();

    // ---------------- phase 2: scan of affine maps along chunks, per channel.
    // This block handles channels 2c and 2c+1; thread t owns chunks 2t, 2t+1.
    // Compose (later ∘ earlier): (A2,K2)∘(A1,K1) = (A2*A1, A2*K1+K2).
    for (int half = 0; half < 2; ++half) {
        const int d = (c << 1) | half;
        const size_t i0 = ((size_t)b * C_ + 2 * t)     * DH_ + d;
        const size_t i1 = ((size_t)b * C_ + 2 * t + 1) * DH_ + d;
        const float a0 = agg_a[i0], k0 = agg_kv[i0];
        const float a1 = agg_a[i1], k1 = agg_kv[i1];
        float am = a1 * a0;             // inclusive composite of own pair
        float km = fmaf(a1, k0, k1);
        __syncthreads();                // protect LDS reuse across halves
        sa[t] = am; sk[t] = km;
        __syncthreads();
        for (int o = 1; o < 128; o <<= 1) {
            float ap = 1.f, kp = 0.f;
            if (t >= o) { ap = sa[t - o]; kp = sk[t - o]; }
            __syncthreads();            // all reads before any writes
            km = fmaf(am, kp, km);      // own ∘ partner(earlier)
            am = am * ap;
            sa[t] = am; sk[t] = km;
            __syncthreads();
        }
        // h_init = 0 => h0 is the K-part of the exclusive composite.
        const float ke = (t > 0) ? sk[t - 1] : 0.f;   // excl. before chunk 2t
        h0[i0] = ke;
        h0[i1] = fmaf(a0, ke, k0);                    // after applying chunk 2t
    }

    cg::this_grid().sync();

    // ---------------- phase 3: recompute chunk with carried state, write out.
    {
        float h[4];
        const f32x4 hv = *(const f32x4*)(h0 + ((size_t)b * C_ + c) * DH_ + d4);
#pragma unroll
        for (int j = 0; j < 4; ++j) h[j] = hv[j];

        float* ob = out + ((size_t)b * T_ + (size_t)c * TC_) * DH_;
#pragma unroll 4
        for (int i = 0; i < TC_; ++i) {
            const float* r = xb + (size_t)i * ROW_;
            const f32x4 xi = *(const f32x4*)(r + d4);        // L3 hit (phase 1)
            const f32x4 gi = *(const f32x4*)(r + DH_ + d4);  // L3 hit
            const f32x4 go = *(const f32x4*)(r + 2 * DH_ + d4);
            f32x4 o;
#pragma unroll
            for (int j = 0; j < 4; ++j) {
                const float s  = sigmoid_f(gi[j]);
                const float f  = 1.0f - s;
                const float iv = tanh_f(xi[j]) * s;
                h[j] = fmaf(f, h[j], iv);
                o[j] = tanh_f(h[j]) * sigmoid_f(go[j]);
            }
            __builtin_nontemporal_store(o, (f32x4*)(ob + (size_t)i * DH_ + d4));
        }
    }
}

// Fallback (no usable workspace): sequential per-channel pass. Correct, slow.
__global__ void k_seq(const float* __restrict__ x, float* __restrict__ out) {
    const int b = blockIdx.x;
    const int d4 = threadIdx.x << 2;
    const float* xb = x + (size_t)b * T_ * ROW_;
    float* ob = out + (size_t)b * T_ * DH_;
    float h[4] = {0.f, 0.f, 0.f, 0.f};
    for (int i = 0; i < T_; ++i) {
        const float* r = xb + (size_t)i * ROW_;
        const f32x4 xi = *(const f32x4*)(r + d4);
        const f32x4 gi = *(const f32x4*)(r + DH_ + d4);
        const f32x4 go = *(const f32x4*)(r + 2 * DH_ + d4);
        f32x4 o;
#pragma unroll
        for (int j = 0; j < 4; ++j) {
            const float s  = sigmoid_f(gi[j]);
            const float f  = 1.0f - s;
            const float iv = tanh_f(xi[j]) * s;
            h[j] = fmaf(f, h[j], iv);
            o[j] = tanh_f(h[j]) * sigmoid_f(go[j]);
        }
        *(f32x4*)(ob + (size_t)i * DH_ + d4) = o;
    }
}

extern "C" void kernel_launch(void* const* d_in, const int* in_sizes, int n_in,
                              void* d_out, int out_size, void* d_ws, size_t ws_size,
                              hipStream_t stream) {
    const float* x = (const float*)d_in[0];
    float* out = (float*)d_out;

    const size_t n_agg = (size_t)B_ * C_ * DH_;          // 512K floats = 2 MiB
    if (ws_size < 3 * n_agg * sizeof(float)) {
        hipLaunchKernelGGL(k_seq, dim3(B_), dim3(DH_ / 4), 0, stream, x, out);
        return;
    }

    float* agg_a  = (float*)d_ws;
    float* agg_kv = agg_a  + n_agg;
    float* h0     = agg_kv + n_agg;

    void* kargs[] = {(void*)&x, (void*)&out, (void*)&agg_a,
                     (void*)&agg_kv, (void*)&h0};
    hipLaunchCooperativeKernel((const void*)k_fused, dim3(C_, B_), dim3(128),
                               kargs, 0, stream);
}

// Round 13
// 332.667 us; speedup vs baseline: 1.6575x; 1.6575x over previous
//
#include <hip/hip_runtime.h>

// AssociativeScanGateLoop: h_t = f_t*h_{t-1} + i_t*v_t per (b,d) sequence.
// x: (B=4, T=8192, 3*512) fp32.  out: (4, 8192, 512) fp32.
//
// v6: attack the measured latency bound (v5 counters: VALUBusy 5.9%,
// HBM 10.5%, Occ 23.8% => stall-dominated). Changes vs v4 (316us best):
//   - C 256 -> 512: 2048 blocks for K1/K2 (16 waves/CU, was 8)
//   - Tc=16 compile-time + full unroll: all chunk loads address-independent
//     so the scheduler can keep many 16B loads in flight per wave
//   - KS stays Kogge-Stone (parallel), now 512 threads x 2048 blocks
// No cooperative launch (v5 showed ~215us/iter host overhead for coop).

#define B_   4
#define T_   8192
#define DH_  512
#define ROW_ 1536
#define C_   512
#define TC_  16          // T_ / C_

// clang ext-vector: __builtin_nontemporal_store requires this, not HIP float4.
typedef float f32x4 __attribute__((ext_vector_type(4)));

__device__ __forceinline__ float rcp_f(float x) {
    return __builtin_amdgcn_rcpf(x);   // v_rcp_f32 — avoids div expansion
}
__device__ __forceinline__ float sigmoid_f(float x) {
    return rcp_f(1.0f + __expf(-x));
}
__device__ __forceinline__ float tanh_f(float x) {
    // 1 - 2/(e^{2x}+1): saturates to +/-1 even when __expf overflows to inf.
    return 1.0f - 2.0f * rcp_f(__expf(2.0f * x) + 1.0f);
}

// K1: per-chunk affine aggregate (A, KV). One chunk per block, 128 threads,
// 4 consecutive channels per thread. TC_ fully unrolled: 32 loads with
// independent addresses -> deep MLP per wave.
__global__ void k_partials(const float* __restrict__ x,
                           float* __restrict__ agg_a,
                           float* __restrict__ agg_kv) {
    const int c = blockIdx.x;
    const int b = blockIdx.y;
    const int d = threadIdx.x << 2;                      // channel base
    const float* xb = x + ((size_t)b * T_ + (size_t)c * TC_) * ROW_;

    float A[4]  = {1.f, 1.f, 1.f, 1.f};
    float KV[4] = {0.f, 0.f, 0.f, 0.f};
#pragma unroll
    for (int i = 0; i < TC_; ++i) {
        const float* r = xb + (size_t)i * ROW_;
        const f32x4 xi = *(const f32x4*)(r + d);
        const f32x4 gi = *(const f32x4*)(r + DH_ + d);
#pragma unroll
        for (int j = 0; j < 4; ++j) {
            const float s  = sigmoid_f(gi[j]);
            const float f  = 1.0f - s;
            const float iv = tanh_f(xi[j]) * s;
            A[j]  = f * A[j];
            KV[j] = fmaf(f, KV[j], iv);
        }
    }
    const size_t idx = ((size_t)b * C_ + c) * DH_ + d;
    f32x4 Av  = {A[0],  A[1],  A[2],  A[3]};
    f32x4 KVv = {KV[0], KV[1], KV[2], KV[3]};
    *(f32x4*)(agg_a + idx)  = Av;
    *(f32x4*)(agg_kv + idx) = KVv;
}

// KS: Kogge-Stone inclusive scan of affine maps (a,kv) over the C_ chunks,
// one block per (b,d) channel, C_ threads (thread c owns chunk c).
// h0[c] = KV-part of the exclusive composite (h_init = 0).
__global__ void k_scan(const float* __restrict__ agg_a,
                       const float* __restrict__ agg_kv,
                       float* __restrict__ h0) {
    __shared__ float sa[C_];
    __shared__ float sk[C_];
    const int d = blockIdx.x;             // channel
    const int b = blockIdx.y;
    const int c = threadIdx.x;            // chunk index

    const size_t idx = ((size_t)b * C_ + c) * DH_ + d;
    float am = agg_a[idx];
    float km = agg_kv[idx];
    sa[c] = am;
    sk[c] = km;
    __syncthreads();

    for (int o = 1; o < C_; o <<= 1) {
        float ap = 1.f, kp = 0.f;
        if (c >= o) { ap = sa[c - o]; kp = sk[c - o]; }
        __syncthreads();                  // all reads before any writes
        km = fmaf(am, kp, km);            // compose: own ∘ prev (uses old am)
        am = am * ap;
        sa[c] = am;
        sk[c] = km;
        __syncthreads();
    }

    h0[idx] = (c == 0) ? 0.f : sk[c - 1];
}

// K2: seed from h0, recompute chunk, write gated output. Unroll 8 (3 streams
// per iteration -> 24 in-flight loads at unroll 8; full 16 would spill).
__global__ void k_apply(const float* __restrict__ x,
                        const float* __restrict__ h0buf,
                        float* __restrict__ out) {
    const int c = blockIdx.x;
    const int b = blockIdx.y;
    const int d = threadIdx.x << 2;

    float h[4];
    const f32x4 hv = *(const f32x4*)(h0buf + ((size_t)b * C_ + c) * DH_ + d);
#pragma unroll
    for (int j = 0; j < 4; ++j) h[j] = hv[j];

    const float* xb = x + ((size_t)b * T_ + (size_t)c * TC_) * ROW_;
    float* ob = out + ((size_t)b * T_ + (size_t)c * TC_) * DH_;

#pragma unroll 8
    for (int i = 0; i < TC_; ++i) {
        const float* r = xb + (size_t)i * ROW_;
        const f32x4 xi = *(const f32x4*)(r + d);
        const f32x4 gi = *(const f32x4*)(r + DH_ + d);
        const f32x4 go = *(const f32x4*)(r + 2 * DH_ + d);
        f32x4 o;
#pragma unroll
        for (int j = 0; j < 4; ++j) {
            const float s  = sigmoid_f(gi[j]);
            const float f  = 1.0f - s;
            const float iv = tanh_f(xi[j]) * s;
            h[j] = fmaf(f, h[j], iv);
            o[j] = tanh_f(h[j]) * sigmoid_f(go[j]);
        }
        // out is never re-read: nontemporal store leaves L3 to x.
        __builtin_nontemporal_store(o, (f32x4*)(ob + (size_t)i * DH_ + d));
    }
}

// Fallback (no usable workspace): sequential per-channel pass. Correct, slow.
__global__ void k_seq(const float* __restrict__ x, float* __restrict__ out) {
    const int b = blockIdx.x;
    const int d4 = threadIdx.x << 2;
    const float* xb = x + (size_t)b * T_ * ROW_;
    float* ob = out + (size_t)b * T_ * DH_;
    float h[4] = {0.f, 0.f, 0.f, 0.f};
    for (int i = 0; i < T_; ++i) {
        const float* r = xb + (size_t)i * ROW_;
        const f32x4 xi = *(const f32x4*)(r + d4);
        const f32x4 gi = *(const f32x4*)(r + DH_ + d4);
        const f32x4 go = *(const f32x4*)(r + 2 * DH_ + d4);
        f32x4 o;
#pragma unroll
        for (int j = 0; j < 4; ++j) {
            const float s  = sigmoid_f(gi[j]);
            const float f  = 1.0f - s;
            const float iv = tanh_f(xi[j]) * s;
            h[j] = fmaf(f, h[j], iv);
            o[j] = tanh_f(h[j]) * sigmoid_f(go[j]);
        }
        *(f32x4*)(ob + (size_t)i * DH_ + d4) = o;
    }
}

extern "C" void kernel_launch(void* const* d_in, const int* in_sizes, int n_in,
                              void* d_out, int out_size, void* d_ws, size_t ws_size,
                              hipStream_t stream) {
    const float* x = (const float*)d_in[0];
    float* out = (float*)d_out;

    const size_t n_agg = (size_t)B_ * C_ * DH_;          // 1M floats = 4 MiB
    if (ws_size < 3 * n_agg * sizeof(float)) {
        hipLaunchKernelGGL(k_seq, dim3(B_), dim3(DH_ / 4), 0, stream, x, out);
        return;
    }

    float* agg_a  = (float*)d_ws;
    float* agg_kv = agg_a  + n_agg;
    float* h0     = agg_kv + n_agg;

    const dim3 grid(C_, B_);
    const dim3 blk(DH_ / 4);   // 128 threads, 4 channels each
    hipLaunchKernelGGL(k_partials, grid, blk, 0, stream, x, agg_a, agg_kv);
    // KS: one block per (b,d) channel, C_ threads each.
    hipLaunchKernelGGL(k_scan, dim3(DH_, B_), dim3(C_), 0, stream,
                       agg_a, agg_kv, h0);
    hipLaunchKernelGGL(k_apply, grid, blk, 0, stream, x, h0, out);
}